// Round 1
// baseline (718.322 us; speedup 1.0000x reference)
//
#include <hip/hip_runtime.h>

// CapsTimeModel forward, f32 baseline (round 1: correctness + sane structure).
// Pipeline:
//   repack pc_w -> wp[n][ic][tap][d16]   (uniform scalar-load friendly)
//   repack fc_w -> fwp[m][n][xd16]
//   conv1+bias+relu -> c (64,128,32,32)
//   conv2+LN0       -> val (64,32,16,16,16)   [19.3 GF, dominant]
//   capsconv<0>+LN1 -> v1 (64,32,7,7,16)      [votes factorized per (n,k,l)]
//   capsconv<1>+LN1 -> v2                      [routing: softmax over m across 32 lanes]
//   fc1+LN2         -> p (64,10,16)
//   fc2(routing)+LN2-> out (64,10,16)

#define EPSLN 1e-5f

// ============================ repack kernels ============================
__global__ __launch_bounds__(256) void k_repack_pcw(const float* __restrict__ pw,
                                                    float* __restrict__ wp) {
    int i = blockIdx.x * 256 + threadIdx.x;       // 512*128*9 = 589824 exact
    int tap = i % 9;
    int ic  = (i / 9) % 128;
    int oc  = i / 1152;
    int n = oc >> 4, d = oc & 15;
    wp[((n * 128 + ic) * 9 + tap) * 16 + d] = pw[i];
}

__global__ __launch_bounds__(256) void k_repack_fw(const float* __restrict__ fw,
                                                   float* __restrict__ fwp) {
    int i = blockIdx.x * 256 + threadIdx.x;       // 1568*4*4*10 = 250880 exact
    int m = i % 10;
    int d = (i / 10) & 3;
    int x = (i / 40) & 3;
    int n = i / 160;
    fwp[(m * 1568 + n) * 16 + x * 4 + d] = fw[i];
}

// ============================ conv1: x -> c ============================
// x(64,3,64,64) --3x3 s2 p1--> c(64,128,32,32), +bias, relu
__global__ __launch_bounds__(256) void k_conv1(const float* __restrict__ x,
                                               const float* __restrict__ bw,
                                               const float* __restrict__ bb,
                                               float* __restrict__ c) {
    int gid = blockIdx.x * 256 + threadIdx.x;     // 8,388,608 outputs
    int w  = gid & 31;
    int h  = (gid >> 5) & 31;
    int oc = (gid >> 10) & 127;
    int b  = gid >> 17;
    const float* xb = x + b * 3 * 64 * 64;
    const float* wb = bw + oc * 27;               // OIHW, uniform per wave -> s_load
    float acc = bb[oc];
    #pragma unroll
    for (int ky = 0; ky < 3; ++ky) {
        int ih = 2 * h + ky - 1;
        if ((unsigned)ih >= 64u) continue;
        #pragma unroll
        for (int kx = 0; kx < 3; ++kx) {
            int iw = 2 * w + kx - 1;
            if ((unsigned)iw >= 64u) continue;
            #pragma unroll
            for (int ic = 0; ic < 3; ++ic)
                acc = fmaf(xb[(ic * 64 + ih) * 64 + iw], wb[ic * 9 + ky * 3 + kx], acc);
        }
    }
    c[gid] = fmaxf(acc, 0.f);
}

// ===================== conv2 + LN0: c -> val =====================
// c(64,128,32,32) --3x3 s2 p1--> u(64,512,16,16); channel oc=n*16+d;
// LN over d(16); store val[b][n][h][w][d].
// One thread computes the full 16-d group for one (b,n,h,w).
__global__ __launch_bounds__(256) void k_conv2_ln0(const float* __restrict__ c,
                                                   const float* __restrict__ wp,
                                                   const float* __restrict__ g,
                                                   const float* __restrict__ bt,
                                                   float* __restrict__ val) {
    int b = blockIdx.x >> 5;
    int n = blockIdx.x & 31;
    int h = threadIdx.x >> 4;
    int w = threadIdx.x & 15;
    const float* cb = c + b * 128 * 1024;
    const float* wn = wp + n * 128 * 144;         // [ic][tap][d16]
    float acc[16];
    #pragma unroll
    for (int j = 0; j < 16; ++j) acc[j] = 0.f;

    for (int ic = 0; ic < 128; ++ic) {
        const float* cp = cb + ic * 1024;
        const float* wt = wn + ic * 144;
        #pragma unroll
        for (int ky = 0; ky < 3; ++ky) {
            int ih = 2 * h + ky - 1;
            if ((unsigned)ih >= 32u) continue;
            #pragma unroll
            for (int kx = 0; kx < 3; ++kx) {
                int iw = 2 * w + kx - 1;
                if ((unsigned)iw >= 32u) continue;
                float in = cp[ih * 32 + iw];
                const float4* w4 = (const float4*)(wt + (ky * 3 + kx) * 16);
                float4 w0 = w4[0], w1 = w4[1], w2 = w4[2], w3 = w4[3];
                acc[0]  = fmaf(in, w0.x, acc[0]);
                acc[1]  = fmaf(in, w0.y, acc[1]);
                acc[2]  = fmaf(in, w0.z, acc[2]);
                acc[3]  = fmaf(in, w0.w, acc[3]);
                acc[4]  = fmaf(in, w1.x, acc[4]);
                acc[5]  = fmaf(in, w1.y, acc[5]);
                acc[6]  = fmaf(in, w1.z, acc[6]);
                acc[7]  = fmaf(in, w1.w, acc[7]);
                acc[8]  = fmaf(in, w2.x, acc[8]);
                acc[9]  = fmaf(in, w2.y, acc[9]);
                acc[10] = fmaf(in, w2.z, acc[10]);
                acc[11] = fmaf(in, w2.w, acc[11]);
                acc[12] = fmaf(in, w3.x, acc[12]);
                acc[13] = fmaf(in, w3.y, acc[13]);
                acc[14] = fmaf(in, w3.z, acc[14]);
                acc[15] = fmaf(in, w3.w, acc[15]);
            }
        }
    }
    // LN over 16
    float mu = 0.f;
    #pragma unroll
    for (int j = 0; j < 16; ++j) mu += acc[j];
    mu *= (1.f / 16.f);
    float var = 0.f;
    #pragma unroll
    for (int j = 0; j < 16; ++j) { float t = acc[j] - mu; var += t * t; }
    var *= (1.f / 16.f);
    float rs = rsqrtf(var + EPSLN);
    float o16[16];
    #pragma unroll
    for (int j = 0; j < 16; ++j) o16[j] = (acc[j] - mu) * rs * g[j] + bt[j];
    float4* dst = (float4*)(val + (((b * 32 + n) * 16 + h) * 16 + w) * 16);
    dst[0] = make_float4(o16[0],  o16[1],  o16[2],  o16[3]);
    dst[1] = make_float4(o16[4],  o16[5],  o16[6],  o16[7]);
    dst[2] = make_float4(o16[8],  o16[9],  o16[10], o16[11]);
    dst[3] = make_float4(o16[12], o16[13], o16[14], o16[15]);
}

// ===================== caps conv step (+optional routing) + LN1 =====================
// Per block: one (b,h,w). 8 groups of 32 lanes; lane = m; each group walks
// (n,k,l) indices it, it+8, ... (36 each). votes[a,d] in regs; softmax over m
// across the 32 lanes of the group; nv accumulated in regs, reduced via LDS.
template <int ROUTING>
__global__ __launch_bounds__(256) void k_capsconv(const float* __restrict__ val,
                                                  const float* __restrict__ cw,
                                                  const float* __restrict__ vprev,
                                                  const float* __restrict__ g,
                                                  const float* __restrict__ bt,
                                                  float* __restrict__ vout) {
    int b  = blockIdx.x / 49;
    int hw = blockIdx.x % 49;
    int h = hw / 7, w = hw % 7;

    __shared__ float4 uloc4[1152];        // (n*9+kl)*4+f : 18.4 KB
    __shared__ float  grp[8 * 544];       // [grp][m(stride 17)*... ] padded
    __shared__ float  nvfin[512];

    // stage unfolded val tile: u[n][k][l][0..15] = val[b][n][2h+k][2w+l][:]
    for (int t = threadIdx.x; t < 1152; t += 256) {
        int f  = t & 3;
        int kl = (t >> 2) % 9;
        int n  = t / 36;
        int k = kl / 3, l = kl % 3;
        const float4* s = (const float4*)(val +
            (((b * 32 + n) * 16 + (2 * h + k)) * 16 + (2 * w + l)) * 16 + f * 4);
        uloc4[t] = *s;
    }

    int lane  = threadIdx.x & 31;   // m
    int grpid = threadIdx.x >> 5;   // 0..7

    float nvp[16];
    if (ROUTING) {
        const float* pv = vprev + (((b * 32 + lane) * 7 + h) * 7 + w) * 16;
        #pragma unroll
        for (int j = 0; j < 16; ++j) nvp[j] = pv[j];
    }
    float nvacc[16];
    #pragma unroll
    for (int j = 0; j < 16; ++j) nvacc[j] = 0.f;

    __syncthreads();

    for (int it = grpid; it < 288; it += 8) {     // it = n*9 + kl
        int n  = it / 9;
        int kl = it % 9;
        float u16[16];
        #pragma unroll
        for (int f = 0; f < 4; ++f) {
            float4 t4 = uloc4[it * 4 + f];
            u16[f * 4 + 0] = t4.x; u16[f * 4 + 1] = t4.y;
            u16[f * 4 + 2] = t4.z; u16[f * 4 + 3] = t4.w;
        }
        // cw (k,l,n,x,d,m): base (kl*32+n)*512 + (x*4+d)*32 + m
        const float* cwb = cw + (kl * 32 + n) * 512 + lane;
        float cwv[16];
        #pragma unroll
        for (int xd = 0; xd < 16; ++xd) cwv[xd] = cwb[xd * 32];
        float votes[16];
        #pragma unroll
        for (int a = 0; a < 4; ++a)
            #pragma unroll
            for (int d = 0; d < 4; ++d) {
                float s = 0.f;
                #pragma unroll
                for (int x = 0; x < 4; ++x)
                    s = fmaf(u16[a * 4 + x], cwv[x * 4 + d], s);
                votes[a * 4 + d] = s;
            }
        float qv;
        if (ROUTING) {
            float qk = 0.f;
            #pragma unroll
            for (int j = 0; j < 16; ++j) qk = fmaf(votes[j], nvp[j], qk);
            qk *= 0.25f;                          // 1/sqrt(16)
            float mx = qk;
            #pragma unroll
            for (int off = 1; off < 32; off <<= 1) mx = fmaxf(mx, __shfl_xor(mx, off));
            float e = __expf(qk - mx);
            float s = e;
            #pragma unroll
            for (int off = 1; off < 32; off <<= 1) s += __shfl_xor(s, off);
            qv = e / s;
        } else {
            qv = 1.0f;
        }
        #pragma unroll
        for (int j = 0; j < 16; ++j) nvacc[j] = fmaf(qv, votes[j], nvacc[j]);
    }

    #pragma unroll
    for (int j = 0; j < 16; ++j) grp[grpid * 544 + lane * 17 + j] = nvacc[j];
    __syncthreads();

    {   // reduce 8 group-partials -> nvfin[512]
        int o = threadIdx.x * 2;
        #pragma unroll
        for (int i = 0; i < 2; ++i, ++o) {
            int mm = o >> 4, j = o & 15;
            float s = 0.f;
            #pragma unroll
            for (int gg = 0; gg < 8; ++gg) s += grp[gg * 544 + mm * 17 + j];
            nvfin[o] = ROUTING ? s : s * (1.f / 32.f);
        }
    }
    __syncthreads();

    if (threadIdx.x < 32) {       // LN per m over 16 (a,d)
        int m = threadIdx.x;
        float v16[16], mu = 0.f;
        #pragma unroll
        for (int j = 0; j < 16; ++j) { v16[j] = nvfin[m * 16 + j]; mu += v16[j]; }
        mu *= (1.f / 16.f);
        float var = 0.f;
        #pragma unroll
        for (int j = 0; j < 16; ++j) { float t = v16[j] - mu; var += t * t; }
        var *= (1.f / 16.f);
        float rs = rsqrtf(var + EPSLN);
        float o16[16];
        #pragma unroll
        for (int j = 0; j < 16; ++j) o16[j] = (v16[j] - mu) * rs * g[j] + bt[j];
        float4* dst = (float4*)(vout + (((b * 32 + m) * 7 + h) * 7 + w) * 16);
        dst[0] = make_float4(o16[0],  o16[1],  o16[2],  o16[3]);
        dst[1] = make_float4(o16[4],  o16[5],  o16[6],  o16[7]);
        dst[2] = make_float4(o16[8],  o16[9],  o16[10], o16[11]);
        dst[3] = make_float4(o16[12], o16[13], o16[14], o16[15]);
    }
}

// ===================== fc step1 + LN2: v2 -> p =====================
// nv[b,m,a,d] = sum_{n,x} fin[b,n,a*4+x] * fwp[m][n][x*4+d] / 10 ; LN -> p(64,10,16)
__global__ __launch_bounds__(256) void k_fc1(const float* __restrict__ fin,
                                             const float* __restrict__ fwp,
                                             const float* __restrict__ g,
                                             const float* __restrict__ bt,
                                             float* __restrict__ p) {
    int b = blockIdx.x / 10, m = blockIdx.x % 10;
    const float* fb = fin + b * 1568 * 16;
    const float* wb = fwp + m * 1568 * 16;
    float acc[16];
    #pragma unroll
    for (int j = 0; j < 16; ++j) acc[j] = 0.f;

    for (int n = threadIdx.x; n < 1568; n += 256) {
        const float4* u4 = (const float4*)(fb + n * 16);
        const float4* w4 = (const float4*)(wb + n * 16);
        float u16[16], w16[16];
        #pragma unroll
        for (int f = 0; f < 4; ++f) {
            float4 a = u4[f], bq = w4[f];
            u16[f * 4 + 0] = a.x;  u16[f * 4 + 1] = a.y;
            u16[f * 4 + 2] = a.z;  u16[f * 4 + 3] = a.w;
            w16[f * 4 + 0] = bq.x; w16[f * 4 + 1] = bq.y;
            w16[f * 4 + 2] = bq.z; w16[f * 4 + 3] = bq.w;
        }
        #pragma unroll
        for (int a = 0; a < 4; ++a)
            #pragma unroll
            for (int d = 0; d < 4; ++d) {
                float s = acc[a * 4 + d];
                #pragma unroll
                for (int x = 0; x < 4; ++x)
                    s = fmaf(u16[a * 4 + x], w16[x * 4 + d], s);
                acc[a * 4 + d] = s;
            }
    }
    // reduce across wave, then across 4 waves
    #pragma unroll
    for (int j = 0; j < 16; ++j)
        #pragma unroll
        for (int off = 1; off < 64; off <<= 1)
            acc[j] += __shfl_xor(acc[j], off);

    __shared__ float red[4][16];
    int wid = threadIdx.x >> 6, ln = threadIdx.x & 63;
    if (ln == 0) {
        #pragma unroll
        for (int j = 0; j < 16; ++j) red[wid][j] = acc[j];
    }
    __syncthreads();
    if (threadIdx.x < 16) {
        int j = threadIdx.x;
        float s = (red[0][j] + red[1][j] + red[2][j] + red[3][j]) * 0.1f; // /M
        float mu = s;
        #pragma unroll
        for (int off = 1; off < 16; off <<= 1) mu += __shfl_xor(mu, off);
        mu *= (1.f / 16.f);
        float t = s - mu;
        float var = t * t;
        #pragma unroll
        for (int off = 1; off < 16; off <<= 1) var += __shfl_xor(var, off);
        var *= (1.f / 16.f);
        float rs = rsqrtf(var + EPSLN);
        p[(b * 10 + m) * 16 + j] = t * rs * g[j] + bt[j];
    }
}

// ===================== fc routing + LN2: v2,p -> out =====================
// 16 groups of 16 lanes; lane = (a,d); group walks n = g, g+16, ... (98 each).
// votes[m] per lane; qk[m] reduced over the 16 (a,d) lanes; softmax over m in-thread.
__global__ __launch_bounds__(256) void k_fc2(const float* __restrict__ fin,
                                             const float* __restrict__ fw,
                                             const float* __restrict__ p,
                                             const float* __restrict__ g,
                                             const float* __restrict__ bt,
                                             float* __restrict__ out) {
    int b = blockIdx.x;
    int ad    = threadIdx.x & 15;   // a*4+d
    int grpid = threadIdx.x >> 4;   // 0..15
    int a = ad >> 2, d = ad & 3;

    float pv[10];
    #pragma unroll
    for (int m = 0; m < 10; ++m) pv[m] = p[(b * 10 + m) * 16 + ad];

    float acc[10];
    #pragma unroll
    for (int m = 0; m < 10; ++m) acc[m] = 0.f;

    const float* fb = fin + b * 1568 * 16;
    for (int n = grpid; n < 1568; n += 16) {
        float4 u4 = *(const float4*)(fb + n * 16 + a * 4);
        const float* wb = fw + n * 160 + d * 10;      // fw[n][x][d][m]
        float votes[10];
        #pragma unroll
        for (int m = 0; m < 10; ++m)
            votes[m] = u4.x * wb[m] + u4.y * wb[40 + m] +
                       u4.z * wb[80 + m] + u4.w * wb[120 + m];
        float qk[10];
        #pragma unroll
        for (int m = 0; m < 10; ++m) {
            float t = votes[m] * pv[m];
            #pragma unroll
            for (int off = 1; off < 16; off <<= 1) t += __shfl_xor(t, off);
            qk[m] = t * 0.25f;                         // 1/sqrt(16)
        }
        float mx = qk[0];
        #pragma unroll
        for (int m = 1; m < 10; ++m) mx = fmaxf(mx, qk[m]);
        float e[10], s = 0.f;
        #pragma unroll
        for (int m = 0; m < 10; ++m) { e[m] = __expf(qk[m] - mx); s += e[m]; }
        float inv = 1.f / s;
        #pragma unroll
        for (int m = 0; m < 10; ++m) acc[m] = fmaf(e[m] * inv, votes[m], acc[m]);
    }

    __shared__ float red[16][16][10];   // [grp][ad][m]
    #pragma unroll
    for (int m = 0; m < 10; ++m) red[grpid][ad][m] = acc[m];
    __syncthreads();

    if (threadIdx.x < 160) {
        int m = threadIdx.x / 16, j = threadIdx.x % 16;
        float s = 0.f;
        #pragma unroll
        for (int gg = 0; gg < 16; ++gg) s += red[gg][j][m];
        float mu = s;
        #pragma unroll
        for (int off = 1; off < 16; off <<= 1) mu += __shfl_xor(mu, off);
        mu *= (1.f / 16.f);
        float t = s - mu;
        float var = t * t;
        #pragma unroll
        for (int off = 1; off < 16; off <<= 1) var += __shfl_xor(var, off);
        var *= (1.f / 16.f);
        float rs = rsqrtf(var + EPSLN);
        out[(b * 10 + m) * 16 + j] = t * rs * g[j] + bt[j];
    }
}

// ============================ launch ============================
extern "C" void kernel_launch(void* const* d_in, const int* in_sizes, int n_in,
                              void* d_out, int out_size, void* d_ws, size_t ws_size,
                              hipStream_t stream) {
    const float* x    = (const float*)d_in[0];
    const float* bbw  = (const float*)d_in[1];
    const float* bbb  = (const float*)d_in[2];
    const float* pcw  = (const float*)d_in[3];
    const float* ln0g = (const float*)d_in[4];
    const float* ln0b = (const float*)d_in[5];
    const float* cwt  = (const float*)d_in[6];
    const float* ln1g = (const float*)d_in[7];
    const float* ln1b = (const float*)d_in[8];
    const float* fw   = (const float*)d_in[9];
    const float* ln2g = (const float*)d_in[10];
    const float* ln2b = (const float*)d_in[11];
    float* outp = (float*)d_out;

    float* ws  = (float*)d_ws;
    float* c    = ws;                   // 8,388,608
    float* val  = c   + 8388608;        // 8,388,608
    float* v1   = val + 8388608;        // 1,605,632
    float* v2   = v1  + 1605632;        // 1,605,632
    float* wp   = v2  + 1605632;        //   589,824
    float* fwp  = wp  + 589824;         //   250,880
    float* p    = fwp + 250880;         //    10,240  (total ~83.4 MB)

    k_repack_pcw<<<2304, 256, 0, stream>>>(pcw, wp);
    k_repack_fw <<<980,  256, 0, stream>>>(fw, fwp);
    k_conv1     <<<32768, 256, 0, stream>>>(x, bbw, bbb, c);
    k_conv2_ln0 <<<2048, 256, 0, stream>>>(c, wp, ln0g, ln0b, val);
    k_capsconv<0><<<3136, 256, 0, stream>>>(val, cwt, nullptr, ln1g, ln1b, v1);
    k_capsconv<1><<<3136, 256, 0, stream>>>(val, cwt, v1, ln1g, ln1b, v2);
    k_fc1       <<<640, 256, 0, stream>>>(v2, fwp, ln2g, ln2b, p);
    k_fc2       <<<64, 256, 0, stream>>>(v2, fw, p, ln2g, ln2b, outp);
}

// Round 5
// 501.311 us; speedup vs baseline: 1.4329x; 1.4329x over previous
//
#include <hip/hip_runtime.h>

// CapsTimeModel forward, round 5: R3 + FIXED workspace layout.
// ROOT CAUSE of R2-R4 failures: val is (64,512,16,16) = 8,388,608 floats; the
// R2-R4 layouts reserved only 2,097,152 -> conv2 output overflowed into
// v1/v2/fwp/p and capsconv read clobbered memory. MFMA kernel was never wrong.
// This round: MFMA conv2 authoritative, bisect scaffolding removed.

#define EPSLN 1e-5f

typedef short  short8 __attribute__((ext_vector_type(8)));
typedef __bf16 bf16x8 __attribute__((ext_vector_type(8)));
typedef float  f32x4  __attribute__((ext_vector_type(4)));

union Frag { short8 s; bf16x8 b; };

// ============================ repack kernels ============================
__global__ __launch_bounds__(256) void k_repack_bw(const float* __restrict__ bw,
                                                   float* __restrict__ bwT) {
    int i = blockIdx.x * 256 + threadIdx.x;       // 128*27 = 3456
    if (i >= 3456) return;
    int oc = i / 27, r = i % 27;
    bwT[r * 128 + oc] = bw[i];
}

__global__ __launch_bounds__(256) void k_repack_pcw(const float* __restrict__ pw,
                                                    __bf16* __restrict__ wbT) {
    int i = blockIdx.x * 256 + threadIdx.x;       // 512*1152 = 589824 exact
    int oc = i / 1152, r = i % 1152;
    int ic = r / 9, tap = r % 9;
    wbT[oc * 1152 + tap * 128 + ic] = (__bf16)pw[i];
}

__global__ __launch_bounds__(256) void k_repack_fw(const float* __restrict__ fw,
                                                   float* __restrict__ fwp) {
    int i = blockIdx.x * 256 + threadIdx.x;       // 250880 exact
    int m = i % 10;
    int d = (i / 10) & 3;
    int x = (i / 40) & 3;
    int n = i / 160;
    fwp[(m * 1568 + n) * 16 + x * 4 + d] = fw[i];
}

// ==================== conv1: x -> c2p (NHWC bf16, padded) ====================
__global__ __launch_bounds__(256) void k_conv1(const float* __restrict__ x,
                                               const float* __restrict__ bwT,
                                               const float* __restrict__ bb,
                                               __bf16* __restrict__ c2p) {
    int gid = blockIdx.x * 256 + threadIdx.x;     // 64*32*32*128 = 8,388,608
    int oc = gid & 127;
    int p  = gid >> 7;
    int w = p & 31, h = (p >> 5) & 31, b = p >> 10;
    const float* xb = x + b * 3 * 64 * 64;
    float acc = bb[oc];
    #pragma unroll
    for (int ky = 0; ky < 3; ++ky) {
        int ih = 2 * h + ky - 1;
        if ((unsigned)ih >= 64u) continue;
        #pragma unroll
        for (int kx = 0; kx < 3; ++kx) {
            int iw = 2 * w + kx - 1;
            if ((unsigned)iw >= 64u) continue;
            #pragma unroll
            for (int ic = 0; ic < 3; ++ic)
                acc = fmaf(xb[(ic * 64 + ih) * 64 + iw],
                           bwT[(ic * 9 + ky * 3 + kx) * 128 + oc], acc);
        }
    }
    c2p[((b * 34 + h + 1) * 34 + (w + 1)) * 128 + oc] = (__bf16)fmaxf(acc, 0.f);
}

// ==================== conv2: MFMA GEMM + fused LN0 -> val ====================
// A[p][k] = c2p[b][2oh+ty][2ow+tx][ic], k = tap*128+ic ; B^T = wbT[oc][k]
__global__ __launch_bounds__(256) void k_conv2_mfma(const __bf16* __restrict__ c2p,
                                                    const __bf16* __restrict__ wbT,
                                                    const float* __restrict__ g,
                                                    const float* __restrict__ bt,
                                                    float* __restrict__ val) {
    __shared__ unsigned short sA[128 * 32];   // [row][k] bf16 bits, 8 KB
    __shared__ unsigned short sB[64 * 32];    // [oc][k]  bf16 bits, 4 KB

    const int t = threadIdx.x;
    const int mblk = blockIdx.x >> 3, nblk = blockIdx.x & 7;
    const int pbase = mblk * 128, ocbase = nblk * 64;
    const int b = pbase >> 8;                 // 2 m-blocks per image

    const int r0 = t >> 2, r1 = r0 + 64;      // A rows this thread stages
    const int kc8 = (t & 3) * 8;              // k-offset within 32-chunk
    const int oh0 = ((pbase + r0) >> 4) & 15, ow0 = (pbase + r0) & 15;
    const int oh1 = ((pbase + r1) >> 4) & 15, ow1 = (pbase + r1) & 15;

    const unsigned short* cb = (const unsigned short*)c2p + (size_t)b * 147968;
    const unsigned short* ws = (const unsigned short*)wbT
                               + (ocbase + (t >> 2)) * 1152 + kc8;

    const int lane = t & 63, wid = t >> 6;
    const int lo = lane & 15, hi = lane >> 4;

    f32x4 acc[2][4];
    #pragma unroll
    for (int fr = 0; fr < 2; ++fr)
        #pragma unroll
        for (int fc = 0; fc < 4; ++fc)
            acc[fr][fc] = (f32x4){0.f, 0.f, 0.f, 0.f};

    for (int ks = 0; ks < 36; ++ks) {
        const int tap = ks / 4;               // conv tap = ky*3+kx
        const int ic0 = (ks % 4) * 32;        // ic chunk base
        const int ty = tap / 3, tx = tap % 3;
        uint4 a0 = *(const uint4*)(cb + ((2 * oh0 + ty) * 34 + (2 * ow0 + tx)) * 128
                                      + ic0 + kc8);
        uint4 a1 = *(const uint4*)(cb + ((2 * oh1 + ty) * 34 + (2 * ow1 + tx)) * 128
                                      + ic0 + kc8);
        uint4 b0 = *(const uint4*)(ws + ks * 32);
        __syncthreads();                      // prior iteration's reads complete
        *(uint4*)&sA[(unsigned)t * 8]         = a0;
        *(uint4*)&sA[((unsigned)t + 256) * 8] = a1;
        *(uint4*)&sB[(unsigned)t * 8]         = b0;
        __syncthreads();                      // tile visible to all waves

        Frag af0, af1, bf[4];
        af0.s = *(const short8*)&sA[(wid * 32 + lo) * 32 + hi * 8];
        af1.s = *(const short8*)&sA[(wid * 32 + 16 + lo) * 32 + hi * 8];
        #pragma unroll
        for (int fc = 0; fc < 4; ++fc)
            bf[fc].s = *(const short8*)&sB[(fc * 16 + lo) * 32 + hi * 8];
        #pragma unroll
        for (int fc = 0; fc < 4; ++fc) {
            acc[0][fc] = __builtin_amdgcn_mfma_f32_16x16x32_bf16(
                af0.b, bf[fc].b, acc[0][fc], 0, 0, 0);
            acc[1][fc] = __builtin_amdgcn_mfma_f32_16x16x32_bf16(
                af1.b, bf[fc].b, acc[1][fc], 0, 0, 0);
        }
    }

    // epilogue: C/D lane map: col(=d) = lane&15, row(=pixel) = hi*4 + j
    const float gv = g[lo], bv = bt[lo];
    #pragma unroll
    for (int fr = 0; fr < 2; ++fr) {
        #pragma unroll
        for (int fc = 0; fc < 4; ++fc) {
            const int n = (ocbase >> 4) + fc;
            #pragma unroll
            for (int j = 0; j < 4; ++j) {
                float v = acc[fr][fc][j];
                float s1 = v, s2 = v * v;
                #pragma unroll
                for (int off = 1; off < 16; off <<= 1) {
                    s1 += __shfl_xor(s1, off);
                    s2 += __shfl_xor(s2, off);
                }
                float mu  = s1 * (1.f / 16.f);
                float var = s2 * (1.f / 16.f) - mu * mu;
                float rs  = rsqrtf(var + EPSLN);
                float o   = (v - mu) * rs * gv + bv;
                int p  = pbase + wid * 32 + fr * 16 + hi * 4 + j;
                int oh = (p >> 4) & 15, ow = p & 15;
                val[(((b * 32 + n) * 16 + oh) * 16 + ow) * 16 + lo] = o;
            }
        }
    }
}

// ===================== caps conv step (+optional routing) + LN1 =====================
template <int ROUTING>
__global__ __launch_bounds__(256) void k_capsconv(const float* __restrict__ val,
                                                  const float* __restrict__ cw,
                                                  const float* __restrict__ vprev,
                                                  const float* __restrict__ g,
                                                  const float* __restrict__ bt,
                                                  float* __restrict__ vout) {
    int b  = blockIdx.x / 49;
    int hw = blockIdx.x % 49;
    int h = hw / 7, w = hw % 7;

    __shared__ float4 uloc4[1152];
    __shared__ float  grp[8 * 544];
    __shared__ float  nvfin[512];

    for (int t = threadIdx.x; t < 1152; t += 256) {
        int f  = t & 3;
        int kl = (t >> 2) % 9;
        int n  = t / 36;
        int k = kl / 3, l = kl % 3;
        const float4* s = (const float4*)(val +
            (((b * 32 + n) * 16 + (2 * h + k)) * 16 + (2 * w + l)) * 16 + f * 4);
        uloc4[t] = *s;
    }

    int lane  = threadIdx.x & 31;   // m
    int grpid = threadIdx.x >> 5;   // 0..7

    float nvp[16];
    if (ROUTING) {
        const float* pv = vprev + (((b * 32 + lane) * 7 + h) * 7 + w) * 16;
        #pragma unroll
        for (int j = 0; j < 16; ++j) nvp[j] = pv[j];
    }
    float nvacc[16];
    #pragma unroll
    for (int j = 0; j < 16; ++j) nvacc[j] = 0.f;

    __syncthreads();

    for (int it = grpid; it < 288; it += 8) {
        int n  = it / 9;
        int kl = it % 9;
        float u16[16];
        #pragma unroll
        for (int f = 0; f < 4; ++f) {
            float4 t4 = uloc4[it * 4 + f];
            u16[f * 4 + 0] = t4.x; u16[f * 4 + 1] = t4.y;
            u16[f * 4 + 2] = t4.z; u16[f * 4 + 3] = t4.w;
        }
        const float* cwb = cw + (kl * 32 + n) * 512 + lane;
        float cwv[16];
        #pragma unroll
        for (int xd = 0; xd < 16; ++xd) cwv[xd] = cwb[xd * 32];
        float votes[16];
        #pragma unroll
        for (int a = 0; a < 4; ++a)
            #pragma unroll
            for (int d = 0; d < 4; ++d) {
                float s = 0.f;
                #pragma unroll
                for (int x = 0; x < 4; ++x)
                    s = fmaf(u16[a * 4 + x], cwv[x * 4 + d], s);
                votes[a * 4 + d] = s;
            }
        float qv;
        if (ROUTING) {
            float qk = 0.f;
            #pragma unroll
            for (int j = 0; j < 16; ++j) qk = fmaf(votes[j], nvp[j], qk);
            qk *= 0.25f;
            float mx = qk;
            #pragma unroll
            for (int off = 1; off < 32; off <<= 1) mx = fmaxf(mx, __shfl_xor(mx, off));
            float e = __expf(qk - mx);
            float s = e;
            #pragma unroll
            for (int off = 1; off < 32; off <<= 1) s += __shfl_xor(s, off);
            qv = e / s;
        } else {
            qv = 1.0f;
        }
        #pragma unroll
        for (int j = 0; j < 16; ++j) nvacc[j] = fmaf(qv, votes[j], nvacc[j]);
    }

    #pragma unroll
    for (int j = 0; j < 16; ++j) grp[grpid * 544 + lane * 17 + j] = nvacc[j];
    __syncthreads();

    {
        int o = threadIdx.x * 2;
        #pragma unroll
        for (int i = 0; i < 2; ++i, ++o) {
            int mm = o >> 4, j = o & 15;
            float s = 0.f;
            #pragma unroll
            for (int gg = 0; gg < 8; ++gg) s += grp[gg * 544 + mm * 17 + j];
            nvfin[o] = ROUTING ? s : s * (1.f / 32.f);
        }
    }
    __syncthreads();

    if (threadIdx.x < 32) {
        int m = threadIdx.x;
        float v16[16], mu = 0.f;
        #pragma unroll
        for (int j = 0; j < 16; ++j) { v16[j] = nvfin[m * 16 + j]; mu += v16[j]; }
        mu *= (1.f / 16.f);
        float var = 0.f;
        #pragma unroll
        for (int j = 0; j < 16; ++j) { float t = v16[j] - mu; var += t * t; }
        var *= (1.f / 16.f);
        float rs = rsqrtf(var + EPSLN);
        float o16[16];
        #pragma unroll
        for (int j = 0; j < 16; ++j) o16[j] = (v16[j] - mu) * rs * g[j] + bt[j];
        float4* dst = (float4*)(vout + (((b * 32 + m) * 7 + h) * 7 + w) * 16);
        dst[0] = make_float4(o16[0],  o16[1],  o16[2],  o16[3]);
        dst[1] = make_float4(o16[4],  o16[5],  o16[6],  o16[7]);
        dst[2] = make_float4(o16[8],  o16[9],  o16[10], o16[11]);
        dst[3] = make_float4(o16[12], o16[13], o16[14], o16[15]);
    }
}

// ===================== fc step1 + LN2: v2 -> p =====================
__global__ __launch_bounds__(256) void k_fc1(const float* __restrict__ fin,
                                             const float* __restrict__ fwp,
                                             const float* __restrict__ g,
                                             const float* __restrict__ bt,
                                             float* __restrict__ p) {
    int b = blockIdx.x / 10, m = blockIdx.x % 10;
    const float* fb = fin + b * 1568 * 16;
    const float* wb = fwp + m * 1568 * 16;
    float acc[16];
    #pragma unroll
    for (int j = 0; j < 16; ++j) acc[j] = 0.f;

    for (int n = threadIdx.x; n < 1568; n += 256) {
        const float4* u4 = (const float4*)(fb + n * 16);
        const float4* w4 = (const float4*)(wb + n * 16);
        float u16[16], w16[16];
        #pragma unroll
        for (int f = 0; f < 4; ++f) {
            float4 a = u4[f], bq = w4[f];
            u16[f * 4 + 0] = a.x;  u16[f * 4 + 1] = a.y;
            u16[f * 4 + 2] = a.z;  u16[f * 4 + 3] = a.w;
            w16[f * 4 + 0] = bq.x; w16[f * 4 + 1] = bq.y;
            w16[f * 4 + 2] = bq.z; w16[f * 4 + 3] = bq.w;
        }
        #pragma unroll
        for (int a = 0; a < 4; ++a)
            #pragma unroll
            for (int d = 0; d < 4; ++d) {
                float s = acc[a * 4 + d];
                #pragma unroll
                for (int x = 0; x < 4; ++x)
                    s = fmaf(u16[a * 4 + x], w16[x * 4 + d], s);
                acc[a * 4 + d] = s;
            }
    }
    #pragma unroll
    for (int j = 0; j < 16; ++j)
        #pragma unroll
        for (int off = 1; off < 64; off <<= 1)
            acc[j] += __shfl_xor(acc[j], off);

    __shared__ float red[4][16];
    int wid = threadIdx.x >> 6, ln = threadIdx.x & 63;
    if (ln == 0) {
        #pragma unroll
        for (int j = 0; j < 16; ++j) red[wid][j] = acc[j];
    }
    __syncthreads();
    if (threadIdx.x < 16) {
        int j = threadIdx.x;
        float s = (red[0][j] + red[1][j] + red[2][j] + red[3][j]) * 0.1f;
        float mu = s;
        #pragma unroll
        for (int off = 1; off < 16; off <<= 1) mu += __shfl_xor(mu, off);
        mu *= (1.f / 16.f);
        float t = s - mu;
        float var = t * t;
        #pragma unroll
        for (int off = 1; off < 16; off <<= 1) var += __shfl_xor(var, off);
        var *= (1.f / 16.f);
        float rs = rsqrtf(var + EPSLN);
        p[(b * 10 + m) * 16 + j] = t * rs * g[j] + bt[j];
    }
}

// ===================== fc routing + LN2: v2,p -> out =====================
__global__ __launch_bounds__(256) void k_fc2(const float* __restrict__ fin,
                                             const float* __restrict__ fw,
                                             const float* __restrict__ p,
                                             const float* __restrict__ g,
                                             const float* __restrict__ bt,
                                             float* __restrict__ out) {
    int b = blockIdx.x;
    int ad    = threadIdx.x & 15;
    int grpid = threadIdx.x >> 4;
    int a = ad >> 2, d = ad & 3;

    float pv[10];
    #pragma unroll
    for (int m = 0; m < 10; ++m) pv[m] = p[(b * 10 + m) * 16 + ad];

    float acc[10];
    #pragma unroll
    for (int m = 0; m < 10; ++m) acc[m] = 0.f;

    const float* fb = fin + b * 1568 * 16;
    for (int n = grpid; n < 1568; n += 16) {
        float4 u4 = *(const float4*)(fb + n * 16 + a * 4);
        const float* wb = fw + n * 160 + d * 10;
        float votes[10];
        #pragma unroll
        for (int m = 0; m < 10; ++m)
            votes[m] = u4.x * wb[m] + u4.y * wb[40 + m] +
                       u4.z * wb[80 + m] + u4.w * wb[120 + m];
        float qk[10];
        #pragma unroll
        for (int m = 0; m < 10; ++m) {
            float t = votes[m] * pv[m];
            #pragma unroll
            for (int off = 1; off < 16; off <<= 1) t += __shfl_xor(t, off);
            qk[m] = t * 0.25f;
        }
        float mx = qk[0];
        #pragma unroll
        for (int m = 1; m < 10; ++m) mx = fmaxf(mx, qk[m]);
        float e[10], s = 0.f;
        #pragma unroll
        for (int m = 0; m < 10; ++m) { e[m] = __expf(qk[m] - mx); s += e[m]; }
        float inv = 1.f / s;
        #pragma unroll
        for (int m = 0; m < 10; ++m) acc[m] = fmaf(e[m] * inv, votes[m], acc[m]);
    }

    __shared__ float red[16][16][10];
    #pragma unroll
    for (int m = 0; m < 10; ++m) red[grpid][ad][m] = acc[m];
    __syncthreads();

    if (threadIdx.x < 160) {
        int m = threadIdx.x / 16, j = threadIdx.x % 16;
        float s = 0.f;
        #pragma unroll
        for (int gg = 0; gg < 16; ++gg) s += red[gg][j][m];
        float mu = s;
        #pragma unroll
        for (int off = 1; off < 16; off <<= 1) mu += __shfl_xor(mu, off);
        mu *= (1.f / 16.f);
        float t = s - mu;
        float var = t * t;
        #pragma unroll
        for (int off = 1; off < 16; off <<= 1) var += __shfl_xor(var, off);
        var *= (1.f / 16.f);
        float rs = rsqrtf(var + EPSLN);
        out[(b * 10 + m) * 16 + j] = t * rs * g[j] + bt[j];
    }
}

// ============================ launch ============================
extern "C" void kernel_launch(void* const* d_in, const int* in_sizes, int n_in,
                              void* d_out, int out_size, void* d_ws, size_t ws_size,
                              hipStream_t stream) {
    const float* x    = (const float*)d_in[0];
    const float* bbw  = (const float*)d_in[1];
    const float* bbb  = (const float*)d_in[2];
    const float* pcw  = (const float*)d_in[3];
    const float* ln0g = (const float*)d_in[4];
    const float* ln0b = (const float*)d_in[5];
    const float* cwt  = (const float*)d_in[6];
    const float* ln1g = (const float*)d_in[7];
    const float* ln1b = (const float*)d_in[8];
    const float* fw   = (const float*)d_in[9];
    const float* ln2g = (const float*)d_in[10];
    const float* ln2b = (const float*)d_in[11];
    float* outp = (float*)d_out;

    // Workspace layout (f32 units). val = 64*512*16*16 = 8,388,608 (R2-R4 bug:
    // was sized 2,097,152 -> overflow clobbered v1/v2/fwp/p).
    float* ws = (float*)d_ws;
    __bf16* c2p = (__bf16*)ws;                 // [0, 4,734,976)   9,469,952 bf16
    __bf16* wbT = (__bf16*)(ws + 4734976);     // [4,734,976, 5,029,888)
    float*  bwT = ws + 5029888;                // [5,029,888, 5,033,344)
    float*  val = ws + 5033344;                // [5,033,344, 13,421,952)
    float*  v1  = ws + 13421952;               // [13,421,952, 15,027,584)
    float*  v2  = ws + 15027584;               // [15,027,584, 16,633,216)
    float*  fwp = ws + 16633216;               // [16,633,216, 16,884,096)
    float*  p   = ws + 16884096;               // [16,884,096, 16,894,336)  ~67.6 MB

    hipMemsetAsync(c2p, 0, (size_t)9469952 * 2, stream);
    k_repack_bw  <<<14,   256, 0, stream>>>(bbw, bwT);
    k_repack_pcw <<<2304, 256, 0, stream>>>(pcw, wbT);
    k_repack_fw  <<<980,  256, 0, stream>>>(fw, fwp);
    k_conv1      <<<32768, 256, 0, stream>>>(x, bwT, bbb, c2p);
    k_conv2_mfma <<<1024, 256, 0, stream>>>(c2p, wbT, ln0g, ln0b, val);
    k_capsconv<0><<<3136, 256, 0, stream>>>(val, cwt, nullptr, ln1g, ln1b, v1);
    k_capsconv<1><<<3136, 256, 0, stream>>>(val, cwt, v1, ln1g, ln1b, v2);
    k_fc1        <<<640, 256, 0, stream>>>(v2, fwp, ln2g, ln2b, p);
    k_fc2        <<<64, 256, 0, stream>>>(v2, fw, p, ln2g, ln2b, outp);
}